// Round 10
// baseline (180.911 us; speedup 1.0000x reference)
//
#include <hip/hip_runtime.h>

#define HID 128
#define NIN 21
#define EIN 2
#define NCLS 4
#define NPB 256   // nodes per block

// ---------------- LDS weight table (per hidden-dim d) ----------------
// Units: u32 words. Row stride 68 u32 = 272 B. Total 128*272 = 34816 B.
//  [0..10]   gi weight pairs (f16x2), scaled by L2E
//  [11..21]  gg weight pairs, scaled by 2*L2E
//  [22..32]  go weight pairs, scaled by L2E
//  [33..53]  nmpn pairs k=0..20: (L2E*W_nmpn[k][d], L2E*W_nmpn[k][128+d])
//  [54..56]  edge gate pairs (i,g,o)
//  [57..59]  f32 node biases bi, bg, bo (scaled)
//  [60..62]  f32 edge biases (scaled)
//  [63..66]  f32 W_fc[c][d]
//  [67]      pad
// d-split is WAVE-level: waves 0-3 read rows 0..63, waves 4-7 rows 64..127.
// Every wave's read remains a single-uniform-address broadcast (round-5's
// lane-level split created 2-address reads + same-bank aliasing; this has
// neither). Partials combined via the small exch[] buffer below.
#define WSTRIDE 68

#define L2E   1.4426950408889634f   // log2(e)
#define L2E2  2.8853900817779268f   // 2*log2(e)

typedef _Float16 h2_t __attribute__((ext_vector_type(2)));

__device__ __forceinline__ unsigned pack_f16(float a, float b) {
    h2_t h;
    h.x = (_Float16)a;
    h.y = (_Float16)b;
    return __builtin_bit_cast(unsigned, h);
}

__device__ __forceinline__ float fdot2_(unsigned a, unsigned b, float c) {
#if __has_builtin(__builtin_amdgcn_fdot2)
    return __builtin_amdgcn_fdot2(__builtin_bit_cast(h2_t, a),
                                  __builtin_bit_cast(h2_t, b), c, false);
#else
    h2_t ha = __builtin_bit_cast(h2_t, a), hb = __builtin_bit_cast(h2_t, b);
    return fmaf((float)ha.x, (float)hb.x, fmaf((float)ha.y, (float)hb.y, c));
#endif
}

__device__ __forceinline__ float rcp_(float x)  { return __builtin_amdgcn_rcpf(x); }
__device__ __forceinline__ float exp2_(float x) { return __builtin_amdgcn_exp2f(x); }
__device__ __forceinline__ float sigmoid_pre(float gp) { return rcp_(1.0f + exp2_(-gp)); }
__device__ __forceinline__ float tanh_pre(float gp) { return fmaf(2.0f, rcp_(1.0f + exp2_(-gp)), -1.0f); }
__device__ __forceinline__ float tanh_(float x) { return fmaf(2.0f, rcp_(1.0f + exp2_(-L2E2 * x)), -1.0f); }

// (512,4): session empirics say min_waves=4 forces the allocator to 64 VGPR.
// Per-thread state here is ~55-60 regs (half the d-range, NPT=1), so 64
// should fit WITHOUT spill -> 8 waves/SIMD allowed; LDS (46KB -> 3 blocks/CU)
// caps residency at 24 waves/CU; grid 782 supplies 3.05 blocks/CU.
// Tripwire: WRITE_SIZE >> 3125 KB means it spilled -> revert to (512,2).
__global__ __launch_bounds__(512, 4)
void fused_gnn_kernel(const float* __restrict__ node_feat,  // N*21
                      const float* __restrict__ edge_feat,  // N*2
                      const float* __restrict__ W_ih_n,     // 512*21
                      const float* __restrict__ b_ih_n,     // 512
                      const float* __restrict__ b_hh_n,     // 512
                      const float* __restrict__ W_ih_e,     // 512*2
                      const float* __restrict__ b_ih_e,     // 512
                      const float* __restrict__ b_hh_e,     // 512
                      const float* __restrict__ W_nmpn,     // 21*256
                      const float* __restrict__ b_nmpn,     // 21
                      const float* __restrict__ W_fc,       // 4*128
                      const float* __restrict__ b_fc,       // 4
                      float* __restrict__ out,              // N*4
                      int N)
{
    __shared__ unsigned ldsu[HID * WSTRIDE];   // 34816 B
    __shared__ unsigned exch[NPB][11];         // 11264 B ; total 46080 B

    const int tid = threadIdx.x;

    // ---------------- stage weight table (threads 0..255) ----------------
    if (tid < HID) {
        const int d = tid;
        unsigned* row = &ldsu[d * WSTRIDE];
        const float* wi = &W_ih_n[(0 * HID + d) * NIN];
        const float* wg = &W_ih_n[(2 * HID + d) * NIN];
        const float* wo = &W_ih_n[(3 * HID + d) * NIN];
#pragma unroll
        for (int j = 0; j < 10; ++j) {
            row[j]      = pack_f16(L2E  * wi[2 * j], L2E  * wi[2 * j + 1]);
            row[11 + j] = pack_f16(L2E2 * wg[2 * j], L2E2 * wg[2 * j + 1]);
            row[22 + j] = pack_f16(L2E  * wo[2 * j], L2E  * wo[2 * j + 1]);
        }
        row[10] = pack_f16(L2E  * wi[20], 0.0f);
        row[21] = pack_f16(L2E2 * wg[20], 0.0f);
        row[32] = pack_f16(L2E  * wo[20], 0.0f);
        row[57] = __float_as_uint(L2E  * (b_ih_n[0 * HID + d] + b_hh_n[0 * HID + d]));
        row[58] = __float_as_uint(L2E2 * (b_ih_n[2 * HID + d] + b_hh_n[2 * HID + d]));
        row[59] = __float_as_uint(L2E  * (b_ih_n[3 * HID + d] + b_hh_n[3 * HID + d]));
    } else if (tid < 2 * HID) {
        const int d = tid - HID;
        unsigned* row = &ldsu[d * WSTRIDE];
#pragma unroll
        for (int k = 0; k < NIN; ++k) {
            row[33 + k] = pack_f16(L2E * W_nmpn[k * 2 * HID + d],
                                   L2E * W_nmpn[k * 2 * HID + HID + d]);
        }
        row[54] = pack_f16(L2E  * W_ih_e[(0 * HID + d) * EIN + 0],
                           L2E  * W_ih_e[(0 * HID + d) * EIN + 1]);
        row[55] = pack_f16(L2E2 * W_ih_e[(2 * HID + d) * EIN + 0],
                           L2E2 * W_ih_e[(2 * HID + d) * EIN + 1]);
        row[56] = pack_f16(L2E  * W_ih_e[(3 * HID + d) * EIN + 0],
                           L2E  * W_ih_e[(3 * HID + d) * EIN + 1]);
        row[60] = __float_as_uint(L2E  * (b_ih_e[0 * HID + d] + b_hh_e[0 * HID + d]));
        row[61] = __float_as_uint(L2E2 * (b_ih_e[2 * HID + d] + b_hh_e[2 * HID + d]));
        row[62] = __float_as_uint(L2E  * (b_ih_e[3 * HID + d] + b_hh_e[3 * HID + d]));
#pragma unroll
        for (int c = 0; c < NCLS; ++c) row[63 + c] = __float_as_uint(W_fc[c * HID + d]);
    }
    __syncthreads();

    // ---------------- assignment: 2 wave-groups per node set ----------------
    const int half = tid >> 8;           // 0: d in [0,64) ; 1: d in [64,128)
    const int nid  = tid & (NPB - 1);    // node slot within block
    const int n    = blockIdx.x * NPB + nid;
    const int nidx = (n < N) ? n : (N - 1);
    const int dbase = half << 6;

    unsigned xnp[11];
#pragma unroll
    for (int j = 0; j < 10; ++j)
        xnp[j] = pack_f16(node_feat[nidx * NIN + 2 * j], node_feat[nidx * NIN + 2 * j + 1]);
    xnp[10] = pack_f16(node_feat[nidx * NIN + 20], 0.0f);
    const unsigned xep = pack_f16(edge_feat[nidx * EIN + 0], edge_feat[nidx * EIN + 1]);

    float acc[NIN];   // partial (this half's d-sum); half0 carries the bias
#pragma unroll
    for (int k = 0; k < NIN; ++k) acc[k] = half ? 0.0f : (L2E * b_nmpn[k]);
    float lg[NCLS];
#pragma unroll
    for (int k = 0; k < NCLS; ++k) lg[k] = half ? 0.0f : b_fc[k];

    // ================= iteration 1 (64 d's per thread) =================
#pragma unroll 2
    for (int dd = 0; dd < 64; ++dd) {
        const unsigned* row = &ldsu[(dbase + dd) * WSTRIDE];

        float gi = __uint_as_float(row[57]);
        float gg = __uint_as_float(row[58]);
        float go = __uint_as_float(row[59]);
#pragma unroll
        for (int j = 0; j < 11; ++j) {
            gi = fdot2_(xnp[j], row[j],      gi);
            gg = fdot2_(xnp[j], row[11 + j], gg);
            go = fdot2_(xnp[j], row[22 + j], go);
        }
        const float cn = sigmoid_pre(gi) * tanh_pre(gg);
        const float hn = sigmoid_pre(go) * tanh_(cn);

        const float ei = fdot2_(xep, row[54], __uint_as_float(row[60]));
        const float eg = fdot2_(xep, row[55], __uint_as_float(row[61]));
        const float eo = fdot2_(xep, row[56], __uint_as_float(row[62]));
        const float ce = sigmoid_pre(ei) * tanh_pre(eg);
        const float he = sigmoid_pre(eo) * tanh_(ce);

        const unsigned hp = pack_f16(he, hn);
#pragma unroll
        for (int k = 0; k < NIN; ++k) acc[k] = fdot2_(hp, row[33 + k], acc[k]);
    }

    // ---------------- combine halves via LDS exchange ----------------
    // (1) half1 posts its partial acc (f16 pairs: ulp ~5e-4, budget 3.3e-2)
    if (half) {
#pragma unroll
        for (int j = 0; j < 10; ++j) exch[nid][j] = pack_f16(acc[2 * j], acc[2 * j + 1]);
        exch[nid][10] = pack_f16(acc[20], 0.0f);
    }
    __syncthreads();
    // (2) half0 adds, applies sigmoid, posts packed xn1
    if (!half) {
#pragma unroll
        for (int j = 0; j < 10; ++j) {
            const h2_t p = __builtin_bit_cast(h2_t, exch[nid][j]);
            xnp[j] = pack_f16(sigmoid_pre(acc[2 * j] + (float)p.x),
                              sigmoid_pre(acc[2 * j + 1] + (float)p.y));
        }
        {
            const h2_t p = __builtin_bit_cast(h2_t, exch[nid][10]);
            xnp[10] = pack_f16(sigmoid_pre(acc[20] + (float)p.x), 0.0f);
        }
#pragma unroll
        for (int j = 0; j < 11; ++j) exch[nid][j] = xnp[j];
    }
    __syncthreads();
    // (3) half1 picks up xn1 (already in the packed form iter2 consumes)
    if (half) {
#pragma unroll
        for (int j = 0; j < 11; ++j) xnp[j] = exch[nid][j];
    }

    // ================= iteration 2 (only h_n matters) =================
#pragma unroll 2
    for (int dd = 0; dd < 64; ++dd) {
        const unsigned* row = &ldsu[(dbase + dd) * WSTRIDE];

        float gi = __uint_as_float(row[57]);
        float gg = __uint_as_float(row[58]);
        float go = __uint_as_float(row[59]);
#pragma unroll
        for (int j = 0; j < 11; ++j) {
            gi = fdot2_(xnp[j], row[j],      gi);
            gg = fdot2_(xnp[j], row[11 + j], gg);
            go = fdot2_(xnp[j], row[22 + j], go);
        }
        const float cn = sigmoid_pre(gi) * tanh_pre(gg);
        const float hn = sigmoid_pre(go) * tanh_(cn);

        lg[0] = fmaf(hn, __uint_as_float(row[63]), lg[0]);
        lg[1] = fmaf(hn, __uint_as_float(row[64]), lg[1]);
        lg[2] = fmaf(hn, __uint_as_float(row[65]), lg[2]);
        lg[3] = fmaf(hn, __uint_as_float(row[66]), lg[3]);
    }

    // ---------------- combine logits + log_softmax + store ----------------
    if (half) {
#pragma unroll
        for (int k = 0; k < NCLS; ++k) exch[nid][k] = __float_as_uint(lg[k]);
    }
    __syncthreads();
    if (!half) {
#pragma unroll
        for (int k = 0; k < NCLS; ++k) lg[k] += __uint_as_float(exch[nid][k]);

        const float m = fmaxf(fmaxf(lg[0], lg[1]), fmaxf(lg[2], lg[3]));
        float s = 0.0f;
#pragma unroll
        for (int k = 0; k < NCLS; ++k) s += exp2_(L2E * (lg[k] - m));
        const float lse = __logf(s) + m;

        if (n < N) {
            float4 o4;
            o4.x = lg[0] - lse;
            o4.y = lg[1] - lse;
            o4.z = lg[2] - lse;
            o4.w = lg[3] - lse;
            *reinterpret_cast<float4*>(&out[n * NCLS]) = o4;
        }
    }
}

extern "C" void kernel_launch(void* const* d_in, const int* in_sizes, int n_in,
                              void* d_out, int out_size, void* d_ws, size_t ws_size,
                              hipStream_t stream)
{
    // setup_inputs order:
    // 0 node_feat, 1 edge_feat, 2 src, 3 dst, 4 W_ih_n, 5 W_hh_n, 6 b_ih_n,
    // 7 b_hh_n, 8 W_ih_e, 9 W_hh_e, 10 b_ih_e, 11 b_hh_e, 12 W_nmpn,
    // 13 b_nmpn, 14 W_empn, 15 b_empn, 16 W_fc, 17 b_fc
    const float* node_feat = (const float*)d_in[0];
    const float* edge_feat = (const float*)d_in[1];
    const float* W_ih_n    = (const float*)d_in[4];
    const float* b_ih_n    = (const float*)d_in[6];
    const float* b_hh_n    = (const float*)d_in[7];
    const float* W_ih_e    = (const float*)d_in[8];
    const float* b_ih_e    = (const float*)d_in[10];
    const float* b_hh_e    = (const float*)d_in[11];
    const float* W_nmpn    = (const float*)d_in[12];
    const float* b_nmpn    = (const float*)d_in[13];
    const float* W_fc      = (const float*)d_in[16];
    const float* b_fc      = (const float*)d_in[17];
    float* out = (float*)d_out;

    const int N = in_sizes[0] / NIN;

    const int block = 512;                      // 8 waves: 2 d-halves x 256 nodes
    const int grid = (N + NPB - 1) / NPB;       // 782 blocks
    fused_gnn_kernel<<<grid, block, 0, stream>>>(
        node_feat, edge_feat,
        W_ih_n, b_ih_n, b_hh_n,
        W_ih_e, b_ih_e, b_hh_e,
        W_nmpn, b_nmpn, W_fc, b_fc,
        out, N);
}